// Round 1
// baseline (390.981 us; speedup 1.0000x reference)
//
#include <hip/hip_runtime.h>
#include <hip/hip_cooperative_groups.h>

namespace cg = cooperative_groups;

// HGCN forward, MI355X — single-dispatch cooperative version.
//
// Live path (reference returns out + 0.0*sum(h_all)):
//   temporal attention #2 (N-reductions -> 12x12 softmax),
//   x @ At2 per node, 1x3 conv over T, flat-order-preserving reshape.
//
// History:
//   R2: memset + atomics + 2 kernels            -> 405 us (passed)
//   R3: fused single kernel, ad-hoc barrier     -> post-timing divergence
//       (theory: missing device-scope fences across per-XCD L2s)
//   R4 (prev best): 2 dispatches, ws partials    -> 346 us (passed)
//   R5 (this): ONE cooperative dispatch. Phase A = k_reduce math,
//       __threadfence() + grid.sync() + __threadfence() (agent-scope
//       release/acquire across XCD L2s), Phase B = k_main math. The x row
//       stays in registers across the barrier (phase B reload removed).
//       Falls back to the proven 2-dispatch path if the cooperative
//       launch is rejected (e.g. by graph capture).
//
// dur_us is dominated (~310 us) by two harness 1.024 GB ws-poison fills at
// ~154 us each (83% of HBM peak — their own roofline). Controllable slice:
// dispatch count, inter-dispatch gap, ~5 us kernel work.

#define NN   8000
#define TT   12
#define FDIM 5
#define NBLK 32   // (NN + 255) / 256

// ---------------------------------------------------------------------------
// Fused cooperative kernel.
// Phase A (per block): partial L/M sums over its 256 nodes via wave shuffles,
//   write 120 partials to ws[blk*120 ..). Phase B (after grid barrier):
//   every block sums the 32 slots, builds the 12x12 attention in LDS, then
//   one thread per n: x2 = x @ At, 1x3 conv over T (pad 1), store.
// Output flat layout (raw reshape): out[o*N*T + n*T + t].
// ---------------------------------------------------------------------------
__global__ __launch_bounds__(256) void k_fused(
    const float* __restrict__ x,    // (N,T,F)
    const float* __restrict__ U1,   // (N,)
    const float* __restrict__ U2,   // (F,N)
    const float* __restrict__ U3,   // (F,)
    const float* __restrict__ be,   // (1,T,T)
    const float* __restrict__ Ve,   // (T,T)
    const float* __restrict__ cw,   // (F,F,1,3)
    const float* __restrict__ cb,   // (F,)
    float*       __restrict__ ws,   // (NBLK,120) partials
    float*       __restrict__ out)  // (F,N,T) flat
{
    __shared__ float red[4][120];
    __shared__ float sE[TT][TT];   // scratch: E
    __shared__ float sAt[TT][TT];  // sigmoid scratch, then final attention
    __shared__ float sW[FDIM][FDIM][3];
    __shared__ float sB[FDIM];
    __shared__ float sL[60];       // L
    __shared__ float sM[60];       // M

    const int tid  = threadIdx.x;
    const int n    = blockIdx.x * 256 + tid;
    const int lane = tid & 63;
    const int wave = tid >> 6;
    const bool act = (n < NN);

    // ---- Phase A: identical math/order to the passing k_reduce -----------
    float xv[TT * FDIM];
    float u1 = 0.f;
    float u2[FDIM];
#pragma unroll
    for (int f = 0; f < FDIM; ++f) u2[f] = 0.f;

    if (act) {
        const float4* xp = (const float4*)(x + (size_t)n * TT * FDIM); // 240B rows, 16B-aligned
#pragma unroll
        for (int i = 0; i < 15; ++i) {
            float4 d = xp[i];
            xv[i * 4 + 0] = d.x; xv[i * 4 + 1] = d.y;
            xv[i * 4 + 2] = d.z; xv[i * 4 + 3] = d.w;
        }
        u1 = U1[n];
#pragma unroll
        for (int f = 0; f < FDIM; ++f) u2[f] = U2[f * NN + n];
    } else {
#pragma unroll
        for (int i = 0; i < TT * FDIM; ++i) xv[i] = 0.f;
    }

    float u3[FDIM];
#pragma unroll
    for (int f = 0; f < FDIM; ++f) u3[f] = U3[f];

    float rhs[TT];
#pragma unroll
    for (int t = 0; t < TT; ++t) {
        float s = 0.f;
#pragma unroll
        for (int f = 0; f < FDIM; ++f) s += u3[f] * xv[t * FDIM + f];
        rhs[t] = s;
    }

    // L partials (values 0..59)
#pragma unroll
    for (int v = 0; v < 60; ++v) {
        float s = xv[v] * u1;
#pragma unroll
        for (int off = 32; off; off >>= 1) s += __shfl_down(s, off);
        if (lane == 0) red[wave][v] = s;
    }
    // M partials (values 60..119), layout 60 + f*12 + t
#pragma unroll
    for (int f = 0; f < FDIM; ++f) {
#pragma unroll
        for (int t = 0; t < TT; ++t) {
            float s = u2[f] * rhs[t];
#pragma unroll
            for (int off = 32; off; off >>= 1) s += __shfl_down(s, off);
            if (lane == 0) red[wave][60 + f * TT + t] = s;
        }
    }

    // stage conv params while partials settle (consumed after later barriers)
    if (tid >= 128 && tid < 203) {
        int q = tid - 128;                 // 75 conv weights, (o,i,0,k) flat
        sW[q / 15][(q % 15) / 3][q % 3] = cw[q];
    }
    if (tid >= 208 && tid < 213) sB[tid - 208] = cb[tid - 208];

    __syncthreads();
    if (tid < 120)
        ws[blockIdx.x * 120 + tid] =
            red[0][tid] + red[1][tid] + red[2][tid] + red[3][tid];

    // ---- grid barrier with agent-scope fences (cross-XCD L2 visibility) --
    __threadfence();                 // release: drain ws writes past this XCD's L2
    cg::this_grid().sync();
    __threadfence();                 // acquire: don't read stale ws from our L2

    // ---- Phase B: identical math/order to the passing k_main -------------
    if (tid < 120) {
        float s = 0.f;
#pragma unroll
        for (int b = 0; b < NBLK; ++b) s += ws[b * 120 + tid];
        if (tid < 60) sL[tid] = s;
        else          sM[tid - 60] = s;
    }
    __syncthreads();

    // S = sigmoid(L @ M + be) into sAt (scratch)
    if (tid < 144) {
        int k = tid / TT, j = tid % TT;
        float p = 0.f;
#pragma unroll
        for (int f = 0; f < FDIM; ++f) p += sL[k * FDIM + f] * sM[f * TT + j];
        p += be[tid];
        sAt[k][j] = 1.f / (1.f + __expf(-p));
    }
    __syncthreads();

    // E = Ve @ S
    if (tid < 144) {
        int i = tid / TT, j = tid % TT;
        float e = 0.f;
#pragma unroll
        for (int k = 0; k < TT; ++k) e += Ve[i * TT + k] * sAt[k][j];
        sE[i][j] = e;
    }
    __syncthreads();

    // softmax over axis i (per column j) -> sAt = attention
    if (tid < TT) {
        int j = tid;
        float m = -1e30f;
#pragma unroll
        for (int i = 0; i < TT; ++i) m = fmaxf(m, sE[i][j]);
        float ex[TT], s = 0.f;
#pragma unroll
        for (int i = 0; i < TT; ++i) { ex[i] = __expf(sE[i][j] - m); s += ex[i]; }
        float inv = 1.f / s;
#pragma unroll
        for (int i = 0; i < TT; ++i) sAt[i][j] = ex[i] * inv;
    }
    __syncthreads();

    if (n >= NN) return;

    // x2[f][t] = sum_t' x[n,t',f] * At[t'][t]  — xv reused from phase A regs
    float x2[FDIM][TT];
#pragma unroll
    for (int f = 0; f < FDIM; ++f) {
#pragma unroll
        for (int t = 0; t < TT; ++t) {
            float s = 0.f;
#pragma unroll
            for (int tp = 0; tp < TT; ++tp) s += xv[tp * FDIM + f] * sAt[tp][t];
            x2[f][t] = s;
        }
    }

    // conv 1x3 over T (pad 1) + bias; 3x float4 stores per (o,n) row
#pragma unroll
    for (int o = 0; o < FDIM; ++o) {
        float res[TT];
#pragma unroll
        for (int t = 0; t < TT; ++t) {
            float a = sB[o];
#pragma unroll
            for (int i = 0; i < FDIM; ++i) {
                if (t > 0)      a += sW[o][i][0] * x2[i][t - 1];
                                a += sW[o][i][1] * x2[i][t];
                if (t < TT - 1) a += sW[o][i][2] * x2[i][t + 1];
            }
            res[t] = a;
        }
        float4* op = (float4*)(out + (size_t)o * NN * TT + (size_t)n * TT);
#pragma unroll
        for (int q = 0; q < 3; ++q)
            op[q] = make_float4(res[4 * q], res[4 * q + 1], res[4 * q + 2], res[4 * q + 3]);
    }
}

// ---------------------------------------------------------------------------
// Fallback path (proven R4 structure) in case the cooperative launch is
// rejected by the runtime / graph capture. Identical math.
// ---------------------------------------------------------------------------
__global__ __launch_bounds__(256) void k_reduce(
    const float* __restrict__ x, const float* __restrict__ U1,
    const float* __restrict__ U2, const float* __restrict__ U3,
    float* __restrict__ ws)
{
    __shared__ float red[4][120];
    const int tid  = threadIdx.x;
    const int n    = blockIdx.x * 256 + tid;
    const int lane = tid & 63;
    const int wave = tid >> 6;
    const bool act = (n < NN);

    float xv[TT * FDIM];
    float u1 = 0.f;
    float u2[FDIM];
#pragma unroll
    for (int f = 0; f < FDIM; ++f) u2[f] = 0.f;

    if (act) {
        const float4* xp = (const float4*)(x + (size_t)n * TT * FDIM);
#pragma unroll
        for (int i = 0; i < 15; ++i) {
            float4 d = xp[i];
            xv[i * 4 + 0] = d.x; xv[i * 4 + 1] = d.y;
            xv[i * 4 + 2] = d.z; xv[i * 4 + 3] = d.w;
        }
        u1 = U1[n];
#pragma unroll
        for (int f = 0; f < FDIM; ++f) u2[f] = U2[f * NN + n];
    } else {
#pragma unroll
        for (int i = 0; i < TT * FDIM; ++i) xv[i] = 0.f;
    }

    float u3[FDIM];
#pragma unroll
    for (int f = 0; f < FDIM; ++f) u3[f] = U3[f];

    float rhs[TT];
#pragma unroll
    for (int t = 0; t < TT; ++t) {
        float s = 0.f;
#pragma unroll
        for (int f = 0; f < FDIM; ++f) s += u3[f] * xv[t * FDIM + f];
        rhs[t] = s;
    }

#pragma unroll
    for (int v = 0; v < 60; ++v) {
        float s = xv[v] * u1;
#pragma unroll
        for (int off = 32; off; off >>= 1) s += __shfl_down(s, off);
        if (lane == 0) red[wave][v] = s;
    }
#pragma unroll
    for (int f = 0; f < FDIM; ++f) {
#pragma unroll
        for (int t = 0; t < TT; ++t) {
            float s = u2[f] * rhs[t];
#pragma unroll
            for (int off = 32; off; off >>= 1) s += __shfl_down(s, off);
            if (lane == 0) red[wave][60 + f * TT + t] = s;
        }
    }
    __syncthreads();
    if (tid < 120)
        ws[blockIdx.x * 120 + tid] =
            red[0][tid] + red[1][tid] + red[2][tid] + red[3][tid];
}

__global__ __launch_bounds__(256) void k_main(
    const float* __restrict__ x,  const float* __restrict__ be,
    const float* __restrict__ Ve, const float* __restrict__ cw,
    const float* __restrict__ cb, const float* __restrict__ ws,
    float* __restrict__ out)
{
    __shared__ float sE[TT][TT];
    __shared__ float sAt[TT][TT];
    __shared__ float sW[FDIM][FDIM][3];
    __shared__ float sB[FDIM];
    __shared__ float sL[60];
    __shared__ float sM[60];

    const int tid = threadIdx.x;

    if (tid < 120) {
        float s = 0.f;
#pragma unroll
        for (int b = 0; b < NBLK; ++b) s += ws[b * 120 + tid];
        if (tid < 60) sL[tid] = s;
        else          sM[tid - 60] = s;
    }
    if (tid >= 128 && tid < 203) {
        int q = tid - 128;
        sW[q / 15][(q % 15) / 3][q % 3] = cw[q];
    }
    if (tid >= 208 && tid < 213) sB[tid - 208] = cb[tid - 208];
    __syncthreads();

    if (tid < 144) {
        int k = tid / TT, j = tid % TT;
        float p = 0.f;
#pragma unroll
        for (int f = 0; f < FDIM; ++f) p += sL[k * FDIM + f] * sM[f * TT + j];
        p += be[tid];
        sAt[k][j] = 1.f / (1.f + __expf(-p));
    }
    __syncthreads();

    if (tid < 144) {
        int i = tid / TT, j = tid % TT;
        float e = 0.f;
#pragma unroll
        for (int k = 0; k < TT; ++k) e += Ve[i * TT + k] * sAt[k][j];
        sE[i][j] = e;
    }
    __syncthreads();

    if (tid < TT) {
        int j = tid;
        float m = -1e30f;
#pragma unroll
        for (int i = 0; i < TT; ++i) m = fmaxf(m, sE[i][j]);
        float ex[TT], s = 0.f;
#pragma unroll
        for (int i = 0; i < TT; ++i) { ex[i] = __expf(sE[i][j] - m); s += ex[i]; }
        float inv = 1.f / s;
#pragma unroll
        for (int i = 0; i < TT; ++i) sAt[i][j] = ex[i] * inv;
    }
    __syncthreads();

    const int n = blockIdx.x * 256 + tid;
    if (n >= NN) return;

    float xv[TT * FDIM];
    {
        const float4* xp = (const float4*)(x + (size_t)n * TT * FDIM);
#pragma unroll
        for (int i = 0; i < 15; ++i) {
            float4 d = xp[i];
            xv[i * 4 + 0] = d.x; xv[i * 4 + 1] = d.y;
            xv[i * 4 + 2] = d.z; xv[i * 4 + 3] = d.w;
        }
    }

    float x2[FDIM][TT];
#pragma unroll
    for (int f = 0; f < FDIM; ++f) {
#pragma unroll
        for (int t = 0; t < TT; ++t) {
            float s = 0.f;
#pragma unroll
            for (int tp = 0; tp < TT; ++tp) s += xv[tp * FDIM + f] * sAt[tp][t];
            x2[f][t] = s;
        }
    }

#pragma unroll
    for (int o = 0; o < FDIM; ++o) {
        float res[TT];
#pragma unroll
        for (int t = 0; t < TT; ++t) {
            float a = sB[o];
#pragma unroll
            for (int i = 0; i < FDIM; ++i) {
                if (t > 0)      a += sW[o][i][0] * x2[i][t - 1];
                                a += sW[o][i][1] * x2[i][t];
                if (t < TT - 1) a += sW[o][i][2] * x2[i][t + 1];
            }
            res[t] = a;
        }
        float4* op = (float4*)(out + (size_t)o * NN * TT + (size_t)n * TT);
#pragma unroll
        for (int q = 0; q < 3; ++q)
            op[q] = make_float4(res[4 * q], res[4 * q + 1], res[4 * q + 2], res[4 * q + 3]);
    }
}

extern "C" void kernel_launch(void* const* d_in, const int* in_sizes, int n_in,
                              void* d_out, int out_size, void* d_ws, size_t ws_size,
                              hipStream_t stream) {
    // setup_inputs order:
    // 0:x 1:adj 2:U1_1 3:U2_1 4:U3_1 5:be_1 6:Ve_1
    // 7:U1_2 8:U2_2 9:U3_2 10:be_2 11:Ve_2
    // 12:conv1_w 13:conv1_b 14:conv2_w 15:conv2_b 16:W_hgc 17:b_hgc
    const float* x  = (const float*)d_in[0];
    const float* U1 = (const float*)d_in[7];
    const float* U2 = (const float*)d_in[8];
    const float* U3 = (const float*)d_in[9];
    const float* be = (const float*)d_in[10];
    const float* Ve = (const float*)d_in[11];
    const float* cw = (const float*)d_in[14];
    const float* cb = (const float*)d_in[15];
    float* ws  = (float*)d_ws;
    float* out = (float*)d_out;

    void* args[] = { (void*)&x, (void*)&U1, (void*)&U2, (void*)&U3, (void*)&be,
                     (void*)&Ve, (void*)&cw, (void*)&cb, (void*)&ws, (void*)&out };
    hipError_t err = hipLaunchCooperativeKernel(
        reinterpret_cast<void*>(k_fused), dim3(NBLK), dim3(256), args, 0, stream);

    if (err != hipSuccess) {
        // proven 2-dispatch fallback (R4 structure)
        k_reduce<<<dim3(NBLK), 256, 0, stream>>>(x, U1, U2, U3, ws);
        k_main<<<dim3(NBLK), 256, 0, stream>>>(x, be, Ve, cw, cb, ws, out);
    }
}

// Round 2
// 328.856 us; speedup vs baseline: 1.1889x; 1.1889x over previous
//
#include <hip/hip_runtime.h>

// HGCN forward, MI355X — 2-dispatch deterministic version, LDS-transpose reduce.
//
// Live path (reference returns out + 0.0*sum(h_all)):
//   temporal attention #2 (N-reductions -> 12x12 softmax),
//   x @ At2 per node, 1x3 conv over T, flat-order-preserving reshape.
//
// History:
//   R2: memset + atomics + 2 kernels          -> 405 us (passed)
//   R3: fused single kernel, ad-hoc barrier   -> post-timing divergence
//   R4: 2 dispatches, ws partials, shuffles   -> 346 us (passed, prev best)
//   R5: single cooperative dispatch           -> 391 us (passed; coop launch
//       itself costs ~45 us in graph replay — dispatch count is NOT the lever)
//   R6 (this): back to 2 plain dispatches; k_reduce rebuilt as 125 blocks x
//       64 threads (125*64 = 8000 exactly, no bounds checks, 1 wave/block)
//       with an LDS-transpose reduction: 248 DS wave-ops/block instead of
//       ~2880 shuffle ops across 4 waves. Deterministic (fixed order).
//
// dur_us floor is ~340 us: two harness 1.024 GB ws-poison fills at ~154 us
// (83% of HBM peak — their own roofline) + ~30 us of fixed restore
// dispatches. Controllable slice: ~5 us of kernel work.

#define NN   8000
#define TT   12
#define FDIM 5
#define RBLK 125   // k_reduce grid: 125 * 64 == 8000
#define MBLK 32    // k_main grid:   32 * 256 >= 8000

// ---------------------------------------------------------------------------
// Kernel A: per-block partial reduction over n. 64 threads (1 wave) / block.
//   slot[blk][0:60]   partial L[t*5+f]  = sum_{n in blk} x[n,t,f] * U1[n]
//   slot[blk][60:120] partial M[f*12+t] = sum_{n in blk} U2[f,n] * rhs[n,t],
//                     rhs[n,t] = sum_f' U3[f'] * x[n,t,f']
// Each lane writes its 120 products to tr[v][lane] (row pad 65 -> 2 lanes/bank,
// conflict-free), then lane l serially sums row l and row 64+l (l<56).
// Block writes ws[blk*120 .. blk*120+120). No atomics, no init required.
// ---------------------------------------------------------------------------
__global__ __launch_bounds__(64) void k_reduce(
    const float* __restrict__ x,    // (N,T,F)
    const float* __restrict__ U1,   // (N,)
    const float* __restrict__ U2,   // (F,N)
    const float* __restrict__ U3,   // (F,)
    float* __restrict__ ws)         // (RBLK, 120) partials
{
    __shared__ float tr[120][65];   // [value][lane], pad 65 -> conflict-free

    const int lane = threadIdx.x;            // 0..63
    const int n    = blockIdx.x * 64 + lane; // < 8000 always (125*64 == 8000)

    float xv[TT * FDIM];
    {
        const float4* xp = (const float4*)(x + (size_t)n * TT * FDIM); // 240B rows, 16B-aligned
#pragma unroll
        for (int i = 0; i < 15; ++i) {
            float4 d = xp[i];
            xv[i * 4 + 0] = d.x; xv[i * 4 + 1] = d.y;
            xv[i * 4 + 2] = d.z; xv[i * 4 + 3] = d.w;
        }
    }
    const float u1 = U1[n];
    float u2[FDIM];
#pragma unroll
    for (int f = 0; f < FDIM; ++f) u2[f] = U2[f * NN + n];
    float u3[FDIM];
#pragma unroll
    for (int f = 0; f < FDIM; ++f) u3[f] = U3[f];

    float rhs[TT];
#pragma unroll
    for (int t = 0; t < TT; ++t) {
        float s = 0.f;
#pragma unroll
        for (int f = 0; f < FDIM; ++f) s += u3[f] * xv[t * FDIM + f];
        rhs[t] = s;
    }

    // transpose into LDS: L products (0..59), M products (60 + f*12 + t)
#pragma unroll
    for (int v = 0; v < 60; ++v) tr[v][lane] = xv[v] * u1;
#pragma unroll
    for (int f = 0; f < FDIM; ++f)
#pragma unroll
        for (int t = 0; t < TT; ++t)
            tr[60 + f * TT + t][lane] = u2[f] * rhs[t];
    __syncthreads();

    // lane l owns value l (and value 64+l for l < 56); serial row sum
    float sA = 0.f;
#pragma unroll
    for (int i = 0; i < 64; ++i) sA += tr[lane][i];
    ws[blockIdx.x * 120 + lane] = sA;

    if (lane < 56) {
        float sB = 0.f;
#pragma unroll
        for (int i = 0; i < 64; ++i) sB += tr[64 + lane][i];
        ws[blockIdx.x * 120 + 64 + lane] = sB;
    }
}

// ---------------------------------------------------------------------------
// Kernel B: every block sums the 125 partial slots (deterministic), builds
// the 12x12 attention in LDS, then one thread per n: x2 = x @ At, 1x3 conv
// over T (pad 1), store. Output flat layout: out[o*N*T + n*T + t].
// ---------------------------------------------------------------------------
__global__ __launch_bounds__(256) void k_main(
    const float* __restrict__ x,    // (N,T,F)
    const float* __restrict__ be,   // (1,T,T)
    const float* __restrict__ Ve,   // (T,T)
    const float* __restrict__ cw,   // (F,F,1,3)
    const float* __restrict__ cb,   // (F,)
    const float* __restrict__ ws,   // (RBLK, 120) partials
    float*       __restrict__ out)  // (F,N,T) flat
{
    __shared__ float sE[TT][TT];   // scratch: E
    __shared__ float sAt[TT][TT];  // sigmoid scratch, then final attention
    __shared__ float sW[FDIM][FDIM][3];
    __shared__ float sB[FDIM];
    __shared__ float sL[60];       // L
    __shared__ float sM[60];       // M

    const int tid = threadIdx.x;

    if (tid < 120) {
        float s = 0.f;
        for (int b = 0; b < RBLK; ++b) s += ws[b * 120 + tid];
        if (tid < 60) sL[tid] = s;
        else          sM[tid - 60] = s;
    }
    if (tid >= 128 && tid < 203) {
        int q = tid - 128;                 // 75 conv weights, (o,i,0,k) flat
        sW[q / 15][(q % 15) / 3][q % 3] = cw[q];
    }
    if (tid >= 208 && tid < 213) sB[tid - 208] = cb[tid - 208];
    __syncthreads();

    // S = sigmoid(L @ M + be) into sAt (scratch)
    if (tid < 144) {
        int k = tid / TT, j = tid % TT;
        float p = 0.f;
#pragma unroll
        for (int f = 0; f < FDIM; ++f) p += sL[k * FDIM + f] * sM[f * TT + j];
        p += be[tid];
        sAt[k][j] = 1.f / (1.f + __expf(-p));
    }
    __syncthreads();

    // E = Ve @ S
    if (tid < 144) {
        int i = tid / TT, j = tid % TT;
        float e = 0.f;
#pragma unroll
        for (int k = 0; k < TT; ++k) e += Ve[i * TT + k] * sAt[k][j];
        sE[i][j] = e;
    }
    __syncthreads();

    // softmax over axis i (per column j) -> sAt = attention
    if (tid < TT) {
        int j = tid;
        float m = -1e30f;
#pragma unroll
        for (int i = 0; i < TT; ++i) m = fmaxf(m, sE[i][j]);
        float ex[TT], s = 0.f;
#pragma unroll
        for (int i = 0; i < TT; ++i) { ex[i] = __expf(sE[i][j] - m); s += ex[i]; }
        float inv = 1.f / s;
#pragma unroll
        for (int i = 0; i < TT; ++i) sAt[i][j] = ex[i] * inv;
    }
    __syncthreads();

    const int n = blockIdx.x * 256 + tid;
    if (n >= NN) return;

    float xv[TT * FDIM];
    {
        const float4* xp = (const float4*)(x + (size_t)n * TT * FDIM);
#pragma unroll
        for (int i = 0; i < 15; ++i) {
            float4 d = xp[i];
            xv[i * 4 + 0] = d.x; xv[i * 4 + 1] = d.y;
            xv[i * 4 + 2] = d.z; xv[i * 4 + 3] = d.w;
        }
    }

    // x2[f][t] = sum_t' x[n,t',f] * At[t'][t]
    float x2[FDIM][TT];
#pragma unroll
    for (int f = 0; f < FDIM; ++f) {
#pragma unroll
        for (int t = 0; t < TT; ++t) {
            float s = 0.f;
#pragma unroll
            for (int tp = 0; tp < TT; ++tp) s += xv[tp * FDIM + f] * sAt[tp][t];
            x2[f][t] = s;
        }
    }

    // conv 1x3 over T (pad 1) + bias; 3x float4 stores per (o,n) row
#pragma unroll
    for (int o = 0; o < FDIM; ++o) {
        float res[TT];
#pragma unroll
        for (int t = 0; t < TT; ++t) {
            float a = sB[o];
#pragma unroll
            for (int i = 0; i < FDIM; ++i) {
                if (t > 0)      a += sW[o][i][0] * x2[i][t - 1];
                                a += sW[o][i][1] * x2[i][t];
                if (t < TT - 1) a += sW[o][i][2] * x2[i][t + 1];
            }
            res[t] = a;
        }
        float4* op = (float4*)(out + (size_t)o * NN * TT + (size_t)n * TT);
#pragma unroll
        for (int q = 0; q < 3; ++q)
            op[q] = make_float4(res[4 * q], res[4 * q + 1], res[4 * q + 2], res[4 * q + 3]);
    }
}

extern "C" void kernel_launch(void* const* d_in, const int* in_sizes, int n_in,
                              void* d_out, int out_size, void* d_ws, size_t ws_size,
                              hipStream_t stream) {
    // setup_inputs order:
    // 0:x 1:adj 2:U1_1 3:U2_1 4:U3_1 5:be_1 6:Ve_1
    // 7:U1_2 8:U2_2 9:U3_2 10:be_2 11:Ve_2
    // 12:conv1_w 13:conv1_b 14:conv2_w 15:conv2_b 16:W_hgc 17:b_hgc
    const float* x  = (const float*)d_in[0];
    const float* U1 = (const float*)d_in[7];
    const float* U2 = (const float*)d_in[8];
    const float* U3 = (const float*)d_in[9];
    const float* be = (const float*)d_in[10];
    const float* Ve = (const float*)d_in[11];
    const float* cw = (const float*)d_in[14];
    const float* cb = (const float*)d_in[15];
    float* ws  = (float*)d_ws;
    float* out = (float*)d_out;

    k_reduce<<<dim3(RBLK), 64, 0, stream>>>(x, U1, U2, U3, ws);
    k_main<<<dim3(MBLK), 256, 0, stream>>>(x, be, Ve, cw, cb, ws, out);
}